// Round 7
// baseline (208.873 us; speedup 1.0000x reference)
//
#include <hip/hip_runtime.h>

typedef unsigned short u16;
typedef __attribute__((ext_vector_type(8))) unsigned short u16x8;
typedef __attribute__((ext_vector_type(8))) short s16x8;
typedef __attribute__((ext_vector_type(4))) float f32x4;

__device__ __forceinline__ u16 f2bf(float f) {
    union { float f; unsigned int u; } c; c.f = f;
    unsigned int u = c.u;
    u += 0x7fffu + ((u >> 16) & 1u);   // RNE
    return (u16)(u >> 16);
}
__device__ __forceinline__ float bf2f(u16 h) {
    union { unsigned int u; float f; } c; c.u = ((unsigned int)h) << 16; return c.f;
}

// async 16B global -> LDS (dest: wave-uniform base, HW adds lane*16)
__device__ __forceinline__ void gload16(const u16* g, u16* l) {
    __builtin_amdgcn_global_load_lds(
        (const __attribute__((address_space(1))) void*)g,
        (__attribute__((address_space(3))) void*)l, 16, 0, 0);
}

// ---------------- cast fp32 -> bf16, 8 elems/thread ----------------
__global__ __launch_bounds__(256) void cast_f32_bf16(const float* __restrict__ in,
                                                     u16* __restrict__ out, int n8) {
    int i = blockIdx.x * 256 + threadIdx.x;
    if (i >= n8) return;
    const float4* p = (const float4*)in;
    float4 a = p[2 * i], b = p[2 * i + 1];
    u16x8 o;
    o[0] = f2bf(a.x); o[1] = f2bf(a.y); o[2] = f2bf(a.z); o[3] = f2bf(a.w);
    o[4] = f2bf(b.x); o[5] = f2bf(b.y); o[6] = f2bf(b.z); o[7] = f2bf(b.w);
    ((u16x8*)out)[i] = o;
}

// ---------------- transpose+cast: src fp32 [R][C] -> dst bf16 [C][R] ----------------
__global__ __launch_bounds__(256) void transpose_cast_f32(const float* __restrict__ src,
                                                          u16* __restrict__ dst, int R, int C) {
    __shared__ u16 t[32][33];
    int tx = threadIdx.x & 31, ty = threadIdx.x >> 5;
    int c0 = blockIdx.x * 32, r0 = blockIdx.y * 32;
#pragma unroll
    for (int i = 0; i < 4; ++i)
        t[ty + i * 8][tx] = f2bf(src[(size_t)(r0 + ty + i * 8) * C + c0 + tx]);
    __syncthreads();
#pragma unroll
    for (int i = 0; i < 4; ++i)
        dst[(size_t)(c0 + ty + i * 8) * R + r0 + tx] = t[tx][ty + i * 8];
}

// ---------------- row softmax over 2048 bf16 cols, in-place ----------------
__global__ __launch_bounds__(256) void softmax_rows_b16(u16* __restrict__ S) {
    const int t = threadIdx.x;
    u16* row = S + (size_t)blockIdx.x * 2048;
    u16x8 a = ((const u16x8*)row)[t];
    float f[8];
#pragma unroll
    for (int j = 0; j < 8; ++j) f[j] = bf2f(a[j]);
    float m = fmaxf(fmaxf(fmaxf(f[0], f[1]), fmaxf(f[2], f[3])),
                    fmaxf(fmaxf(f[4], f[5]), fmaxf(f[6], f[7])));
#pragma unroll
    for (int o = 32; o >= 1; o >>= 1) m = fmaxf(m, __shfl_xor(m, o));
    __shared__ float sm[4], ss[4];
    if ((t & 63) == 0) sm[t >> 6] = m;
    __syncthreads();
    m = fmaxf(fmaxf(sm[0], sm[1]), fmaxf(sm[2], sm[3]));
    float s = 0.f;
#pragma unroll
    for (int j = 0; j < 8; ++j) { f[j] = __expf(f[j] - m); s += f[j]; }
#pragma unroll
    for (int o = 32; o >= 1; o >>= 1) s += __shfl_xor(s, o);
    if ((t & 63) == 0) ss[t >> 6] = s;
    __syncthreads();
    s = (ss[0] + ss[1]) + (ss[2] + ss[3]);
    float inv = 1.f / s;
    u16x8 o8;
#pragma unroll
    for (int j = 0; j < 8; ++j) o8[j] = f2bf(f[j] * inv);
    ((u16x8*)row)[t] = o8;
}

// ======== 128x128 bf16 GEMM, single-buffer (r6, proven): C = A[M,K] * Bt[N,K]^T ========
template<int EPI>
__global__ __launch_bounds__(256, 3) void gemm128(
    const u16* __restrict__ A, const u16* __restrict__ Bt,
    int K, int ldA, int ldBt,
    const float* __restrict__ bias,
    float* __restrict__ outF, int ldOutF,
    u16* __restrict__ outH, int ldOutH,
    u16* __restrict__ Qo, u16* __restrict__ Ko, u16* __restrict__ Vo,
    size_t zA, size_t zBt, size_t zOut) {
    __shared__ u16 lds[16384];
    const int tid  = threadIdx.x;
    const int lane = tid & 63;
    const int wave = tid >> 6;
    const int wrow = wave >> 1, wcol = wave & 1;
    const int lrow = lane & 15;
    const int lkg  = lane >> 4;
    const int bm0  = blockIdx.x * 128;
    const int bn0  = blockIdx.y * 128;
    A  += zA  * blockIdx.z;
    Bt += zBt * blockIdx.z;

    const int srow = tid >> 3;
    const int ssc  = (((tid & 7) * 16) ^ ((srow & 7) << 4)) >> 1;
    const u16* aS[4];
    const u16* bS[4];
#pragma unroll
    for (int g = 0; g < 4; ++g) {
        aS[g] = A  + (size_t)(bm0 + g * 32 + srow) * ldA  + ssc;
        bS[g] = Bt + (size_t)(bn0 + g * 32 + srow) * ldBt + ssc;
    }
    const int dst = wave * 512;

    const int sc0 = (lkg * 16) ^ ((lrow & 7) << 4);
    const int sc1 = (64 + lkg * 16) ^ ((lrow & 7) << 4);

    f32x4 acc[4][4] = {};
    const int NT = K >> 6;

    for (int t = 0; t < NT; ++t) {
#pragma unroll
        for (int g = 0; g < 4; ++g) {
            gload16(aS[g] + (size_t)t * 64, lds + g * 2048 + dst);
            gload16(bS[g] + (size_t)t * 64, lds + 8192 + g * 2048 + dst);
        }
        __syncthreads();
        const char* base = (const char*)lds;
        s16x8 ra[4][2], rb[4][2];
#pragma unroll
        for (int i = 0; i < 4; ++i) {
            const char* p = base + (wrow * 64 + i * 16 + lrow) * 128;
            ra[i][0] = *(const s16x8*)(p + sc0);
            ra[i][1] = *(const s16x8*)(p + sc1);
        }
#pragma unroll
        for (int j = 0; j < 4; ++j) {
            const char* p = base + 16384 + (wcol * 64 + j * 16 + lrow) * 128;
            rb[j][0] = *(const s16x8*)(p + sc0);
            rb[j][1] = *(const s16x8*)(p + sc1);
        }
#pragma unroll
        for (int ks = 0; ks < 2; ++ks)
#pragma unroll
            for (int i = 0; i < 4; ++i)
#pragma unroll
                for (int j = 0; j < 4; ++j)
                    acc[i][j] = __builtin_amdgcn_mfma_f32_16x16x32_bf16(
                        ra[i][ks], rb[j][ks], acc[i][j], 0, 0, 0);
        __syncthreads();
    }

    if constexpr (EPI == 1) outF += zOut * blockIdx.z;
    else if constexpr (EPI == 2 || EPI == 4) outH += zOut * blockIdx.z;
#pragma unroll
    for (int i = 0; i < 4; ++i) {
        int row0 = bm0 + wrow * 64 + i * 16 + lkg * 4;
#pragma unroll
        for (int j = 0; j < 4; ++j) {
            int col = bn0 + wcol * 64 + j * 16 + lrow;
#pragma unroll
            for (int r = 0; r < 4; ++r) {
                int row = row0 + r;
                float v = acc[i][j][r];
                if constexpr (EPI == 0) {
                    v += bias[col];
                    if (col < 1024)       Qo[(size_t)row * 1024 + col] = f2bf(v * 0.03125f);
                    else if (col < 2048)  Ko[(size_t)row * 1024 + (col - 1024)] = f2bf(v);
                    else                  Vo[(size_t)row * 1024 + (col - 2048)] = f2bf(v);
                } else if constexpr (EPI == 1) {
                    outF[(size_t)row * ldOutF + col] = v;
                } else if constexpr (EPI == 2) {
                    outH[(size_t)row * ldOutH + col] = f2bf(v);
                } else {
                    outH[(size_t)row * ldOutH + col] = f2bf(v + bias[row]);
                }
            }
        }
    }
}

// ======== 256x256 8-phase pipelined bf16 GEMM (m201-faithful): C = A * Bt^T ========
// 512 thr = 8 waves (wm=wave>>2 x wn=wave&3); per-wave 128x64 out = 8x4 frags.
// LDS 128 KiB: 2 bufs x {A0,A1,B0,B1} half-tiles (128 rows x 64 cols bf16 = 16 KB).
// Continuous half-tile issue stream h = globalphase + 7 (order B0,B1,A0,A1 per tile);
// prologue stages h0..h6, vmcnt(6); per tile 4 quadrant phases, each {ds_read subtile,
// stage 1 half, barrier, setprio+16 MFMA, barrier}; vmcnt(6) ONLY at phase 4
// (3 halves in flight), vmcnt(0) for last 3 tiles (drain). 1 block/CU.
template<int MB, int NB>
__device__ __forceinline__ void mfma_quad(f32x4 (&acc)[8][4], const s16x8 (&ra)[4][2],
                                          const s16x8 (&rb)[2][2]) {
    __builtin_amdgcn_s_setprio(1);
#pragma unroll
    for (int ks = 0; ks < 2; ++ks)
#pragma unroll
        for (int i = 0; i < 4; ++i)
#pragma unroll
            for (int j = 0; j < 2; ++j)
                acc[MB + i][NB + j] = __builtin_amdgcn_mfma_f32_16x16x32_bf16(
                    ra[i][ks], rb[j][ks], acc[MB + i][NB + j], 0, 0, 0);
    __builtin_amdgcn_s_setprio(0);
}

template<int EPI>
__global__ __launch_bounds__(512, 2) void gemm256p(
    const u16* __restrict__ A, const u16* __restrict__ Bt,
    int K, int ldA, int ldBt,
    const float* __restrict__ bias,
    u16* __restrict__ outH, int ldOutH,
    u16* __restrict__ Qo, u16* __restrict__ Ko, u16* __restrict__ Vo,
    size_t zA, size_t zBt, size_t zOut) {
    __shared__ u16 lds[65536];          // 128 KiB
    const int tid  = threadIdx.x;
    const int lane = tid & 63;
    const int wave = tid >> 6;
    const int wm   = wave >> 2;         // 0..1
    const int wn   = wave & 3;          // 0..3
    const int lrow = lane & 15;
    const int lkg  = lane >> 4;
    const int bm0  = blockIdx.x * 256;
    const int bn0  = blockIdx.y * 256;
    A  += zA  * blockIdx.z;
    Bt += zBt * blockIdx.z;

    const int NT = K >> 6;

    // ---- staging bases: thread covers local row srow (0..63) of each 64-row round ----
    const int srow = tid >> 3;
    const int ssc  = (((tid & 7) * 16) ^ ((srow & 7) << 4)) >> 1;
    const u16* aBase = A  + (size_t)(bm0 + srow) * ldA  + ssc;
    const u16* bBase = Bt + (size_t)(bn0 + srow) * ldBt + ssc;
    const int dwave  = wave * 512;      // u16; +lane*16B by HW
    // slot u16 base by (h&3): {B0,B1,A0,A1}
    const int slotBase[4] = {16384, 24576, 0, 8192};

#define STAGEH(h)                                                                  \
    if ((h) < 4 * NT) {                                                            \
        const int j_ = (h) >> 2, q_ = (h) & 3, hf_ = q_ & 1;                       \
        const u16* s_ = (q_ & 2) ? aBase : bBase;                                  \
        const int ld_ = (q_ & 2) ? ldA : ldBt;                                     \
        u16* d_ = lds + (j_ & 1) * 32768 + slotBase[q_] + dwave;                   \
        gload16(s_ + (size_t)(hf_ * 128) * ld_ + j_ * 64, d_);                     \
        gload16(s_ + (size_t)(hf_ * 128 + 64) * ld_ + j_ * 64, d_ + 4096);         \
    }

    // ---- frag read addressing ----
    const char* ldsc = (const char*)lds;
    const int sc0 = (lkg * 16) ^ ((lrow & 7) << 4);
    const int sc1 = (64 + lkg * 16) ^ ((lrow & 7) << 4);
    const int aOff = wm * 16384;                 // byte offset of wave's A slot
    const int bOff = 32768 + (wn >> 1) * 16384;  // byte offset of wave's B slot
    const int brow = (wn & 1) * 64;

    f32x4 acc[8][4] = {};
    s16x8 regA[4][2], regB0[2][2], regB1[2][2];

    // ---- prologue: stage h0..h6 (tile0 full + 3/4 of tile1), wait all-but-3 ----
    STAGEH(0) STAGEH(1) STAGEH(2) STAGEH(3) STAGEH(4) STAGEH(5) STAGEH(6)
    asm volatile("s_waitcnt vmcnt(6)" ::: "memory");
    __builtin_amdgcn_s_barrier();

    for (int j = 0; j < NT; ++j) {
        const char* bA = ldsc + (j & 1) * 65536 + aOff;
        const char* bB = ldsc + (j & 1) * 65536 + bOff;
        const int h0 = 4 * j + 7;
        // ---- p0: quadrant (m0-3, n0-1); 12 ds_reads ----
#pragma unroll
        for (int i = 0; i < 4; ++i) {
            const char* p = bA + (i * 16 + lrow) * 128;
            regA[i][0] = *(const s16x8*)(p + sc0);
            regA[i][1] = *(const s16x8*)(p + sc1);
        }
#pragma unroll
        for (int jf = 0; jf < 2; ++jf) {
            const char* p = bB + (brow + jf * 16 + lrow) * 128;
            regB0[jf][0] = *(const s16x8*)(p + sc0);
            regB0[jf][1] = *(const s16x8*)(p + sc1);
        }
        STAGEH(h0)
        __builtin_amdgcn_s_barrier();
        mfma_quad<0, 0>(acc, regA, regB0);
        __builtin_amdgcn_s_barrier();
        // ---- p1: quadrant (m0-3, n2-3); 4 ds_reads ----
#pragma unroll
        for (int jf = 0; jf < 2; ++jf) {
            const char* p = bB + (brow + 32 + jf * 16 + lrow) * 128;
            regB1[jf][0] = *(const s16x8*)(p + sc0);
            regB1[jf][1] = *(const s16x8*)(p + sc1);
        }
        STAGEH(h0 + 1)
        __builtin_amdgcn_s_barrier();
        mfma_quad<0, 2>(acc, regA, regB1);
        __builtin_amdgcn_s_barrier();
        // ---- p2: quadrant (m4-7, n2-3); 8 ds_reads ----
#pragma unroll
        for (int i = 0; i < 4; ++i) {
            const char* p = bA + (64 + i * 16 + lrow) * 128;
            regA[i][0] = *(const s16x8*)(p + sc0);
            regA[i][1] = *(const s16x8*)(p + sc1);
        }
        STAGEH(h0 + 2)
        __builtin_amdgcn_s_barrier();
        mfma_quad<4, 2>(acc, regA, regB1);
        __builtin_amdgcn_s_barrier();
        // ---- p3: quadrant (m4-7, n0-1); stage + counted vmcnt ----
        STAGEH(h0 + 3)
        if (j < NT - 3) {
            asm volatile("s_waitcnt vmcnt(6)" ::: "memory");
        } else {
            asm volatile("s_waitcnt vmcnt(0)" ::: "memory");
        }
        __builtin_amdgcn_s_barrier();
        mfma_quad<4, 0>(acc, regA, regB0);
        __builtin_amdgcn_s_barrier();
    }
#undef STAGEH

    // ---- epilogue: C/D layout col = lane&15, row = (lane>>4)*4 + reg ----
    if constexpr (EPI == 2) outH += zOut * blockIdx.z;
#pragma unroll
    for (int mf = 0; mf < 8; ++mf) {
        int row0 = bm0 + wm * 128 + mf * 16 + lkg * 4;
#pragma unroll
        for (int nf = 0; nf < 4; ++nf) {
            int col = bn0 + wn * 64 + nf * 16 + lrow;
#pragma unroll
            for (int r = 0; r < 4; ++r) {
                int row = row0 + r;
                float v = acc[mf][nf][r];
                if constexpr (EPI == 0) {
                    v += bias[col];
                    if (col < 1024)       Qo[(size_t)row * 1024 + col] = f2bf(v * 0.03125f);
                    else if (col < 2048)  Ko[(size_t)row * 1024 + (col - 1024)] = f2bf(v);
                    else                  Vo[(size_t)row * 1024 + (col - 2048)] = f2bf(v);
                } else {
                    outH[(size_t)row * ldOutH + col] = f2bf(v);
                }
            }
        }
    }
}

extern "C" void kernel_launch(void* const* d_in, const int* in_sizes, int n_in,
                              void* d_out, int out_size, void* d_ws, size_t ws_size,
                              hipStream_t stream) {
    const float* x      = (const float*)d_in[0];
    const float* w_qkv  = (const float*)d_in[1];
    const float* b_qkv  = (const float*)d_in[2];
    const float* w_proj = (const float*)d_in[3];
    const float* b_proj = (const float*)d_in[4];
    float* out = (float*)d_out;
    char* ws = (char*)d_ws;
    (void)in_sizes; (void)n_in; (void)out_size;

    const size_t MB16  = 16777216;
    const size_t BATCH = 2097152;
    const size_t SZB   = 4194304;
    const size_t VPB   = 2097152;

    if (ws_size >= 85983232) {
        u16* xb     = (u16*)(ws);
        u16* Qb     = (u16*)(ws + MB16);
        u16* Kb     = (u16*)(ws + 2 * MB16);
        u16* Vb     = (u16*)(ws + 3 * MB16);
        u16* wqkvT  = (u16*)(ws + 4 * MB16);
        u16* wprojT = (u16*)(ws + 4 * MB16 + 6291456);
        u16* Vpt    = xb;                             // V''^T: 4 x [1024][2048] bf16
        u16* Sb     = Vb;                             // S: 4 x [2048][2048] bf16

        cast_f32_bf16<<<4096, 256, 0, stream>>>(x, xb, 1048576);
        transpose_cast_f32<<<dim3(96, 32), 256, 0, stream>>>(w_qkv, wqkvT, 1024, 3072);
        transpose_cast_f32<<<dim3(32, 32), 256, 0, stream>>>(w_proj, wprojT, 1024, 1024);
        // QKV: 8-phase 256^2 (grid 384)
        gemm256p<0><<<dim3(32, 12), 512, 0, stream>>>(xb, wqkvT, 1024, 1024, 1024,
                                                      b_qkv, nullptr, 0,
                                                      Qb, Kb, Vb, 0, 0, 0);
        // V'' = V*Wp + b_proj (transposed out), gemm128
        gemm128<4><<<dim3(8, 16, 4), 256, 0, stream>>>(wprojT, Vb, 1024, 1024, 1024,
                                                       b_proj, nullptr, 0, Vpt, 2048,
                                                       nullptr, nullptr, nullptr,
                                                       0, BATCH, VPB);
        // S = Q K^T: 8-phase 256^2 (grid 256 = 1.0 round)
        gemm256p<2><<<dim3(8, 8, 4), 512, 0, stream>>>(Qb, Kb, 1024, 1024, 1024,
                                                       nullptr, Sb, 2048,
                                                       nullptr, nullptr, nullptr,
                                                       BATCH, BATCH, SZB);
        softmax_rows_b16<<<8192, 256, 0, stream>>>(Sb);
        // out = P V'' (fp32 direct), gemm128
        gemm128<1><<<dim3(16, 8, 4), 256, 0, stream>>>(Sb, Vpt, 2048, 2048, 2048,
                                                       nullptr, out, 1024, nullptr, 0,
                                                       nullptr, nullptr, nullptr,
                                                       SZB, VPB, BATCH);
    } else {
        // ---- low-memory per-batch plan (<=38 MB): all gemm128 ----
        u16* xbB    = (u16*)(ws);
        u16* QbB    = (u16*)(ws + 4194304);
        u16* KbB    = (u16*)(ws + 8388608);
        u16* VbB    = (u16*)(ws + 12582912);
        u16* VptB   = (u16*)(ws + 16777216);
        u16* Sb     = (u16*)(ws + 20971520);
        u16* wqkvT  = (u16*)(ws + 29360128);
        u16* wprojT = (u16*)(ws + 35651584);

        transpose_cast_f32<<<dim3(96, 32), 256, 0, stream>>>(w_qkv, wqkvT, 1024, 3072);
        transpose_cast_f32<<<dim3(32, 32), 256, 0, stream>>>(w_proj, wprojT, 1024, 1024);
        for (int b = 0; b < 4; ++b) {
            cast_f32_bf16<<<1024, 256, 0, stream>>>(x + (size_t)b * BATCH, xbB, 262144);
            gemm128<0><<<dim3(16, 24), 256, 0, stream>>>(xbB, wqkvT, 1024, 1024, 1024,
                                                         b_qkv, nullptr, 0, nullptr, 0,
                                                         QbB, KbB, VbB, 0, 0, 0);
            gemm128<4><<<dim3(8, 16), 256, 0, stream>>>(wprojT, VbB, 1024, 1024, 1024,
                                                        b_proj, nullptr, 0, VptB, 2048,
                                                        nullptr, nullptr, nullptr, 0, 0, 0);
            gemm128<2><<<dim3(16, 16), 256, 0, stream>>>(QbB, KbB, 1024, 1024, 1024,
                                                         nullptr, nullptr, 0, Sb, 2048,
                                                         nullptr, nullptr, nullptr, 0, 0, 0);
            softmax_rows_b16<<<2048, 256, 0, stream>>>(Sb);
            gemm128<1><<<dim3(16, 8), 256, 0, stream>>>(Sb, VptB, 2048, 2048, 2048,
                                                        nullptr, out + (size_t)b * BATCH, 1024,
                                                        nullptr, 0,
                                                        nullptr, nullptr, nullptr, 0, 0, 0);
        }
    }
}

// Round 9
// 197.565 us; speedup vs baseline: 1.0572x; 1.0572x over previous
//
#include <hip/hip_runtime.h>

typedef unsigned short u16;
typedef __attribute__((ext_vector_type(8))) unsigned short u16x8;
typedef __attribute__((ext_vector_type(8))) short s16x8;
typedef __attribute__((ext_vector_type(4))) float f32x4;

__device__ __forceinline__ u16 f2bf(float f) {
    union { float f; unsigned int u; } c; c.f = f;
    unsigned int u = c.u;
    u += 0x7fffu + ((u >> 16) & 1u);   // RNE
    return (u16)(u >> 16);
}
__device__ __forceinline__ float bf2f(u16 h) {
    union { unsigned int u; float f; } c; c.u = ((unsigned int)h) << 16; return c.f;
}

// async 16B global -> LDS (dest: wave-uniform base, HW adds lane*16)
__device__ __forceinline__ void gload16(const u16* g, u16* l) {
    __builtin_amdgcn_global_load_lds(
        (const __attribute__((address_space(1))) void*)g,
        (__attribute__((address_space(3))) void*)l, 16, 0, 0);
}

// ---------------- cast fp32 -> bf16, 8 elems/thread ----------------
__global__ __launch_bounds__(256) void cast_f32_bf16(const float* __restrict__ in,
                                                     u16* __restrict__ out, int n8) {
    int i = blockIdx.x * 256 + threadIdx.x;
    if (i >= n8) return;
    const float4* p = (const float4*)in;
    float4 a = p[2 * i], b = p[2 * i + 1];
    u16x8 o;
    o[0] = f2bf(a.x); o[1] = f2bf(a.y); o[2] = f2bf(a.z); o[3] = f2bf(a.w);
    o[4] = f2bf(b.x); o[5] = f2bf(b.y); o[6] = f2bf(b.z); o[7] = f2bf(b.w);
    ((u16x8*)out)[i] = o;
}

// ---------------- transpose+cast: src fp32 [R][C] -> dst bf16 [C][R] ----------------
__global__ __launch_bounds__(256) void transpose_cast_f32(const float* __restrict__ src,
                                                          u16* __restrict__ dst, int R, int C) {
    __shared__ u16 t[32][33];
    int tx = threadIdx.x & 31, ty = threadIdx.x >> 5;
    int c0 = blockIdx.x * 32, r0 = blockIdx.y * 32;
#pragma unroll
    for (int i = 0; i < 4; ++i)
        t[ty + i * 8][tx] = f2bf(src[(size_t)(r0 + ty + i * 8) * C + c0 + tx]);
    __syncthreads();
#pragma unroll
    for (int i = 0; i < 4; ++i)
        dst[(size_t)(c0 + ty + i * 8) * R + r0 + tx] = t[tx][ty + i * 8];
}

// ---------------- row softmax over 2048 bf16 cols, in-place ----------------
__global__ __launch_bounds__(256) void softmax_rows_b16(u16* __restrict__ S) {
    const int t = threadIdx.x;
    u16* row = S + (size_t)blockIdx.x * 2048;
    u16x8 a = ((const u16x8*)row)[t];
    float f[8];
#pragma unroll
    for (int j = 0; j < 8; ++j) f[j] = bf2f(a[j]);
    float m = fmaxf(fmaxf(fmaxf(f[0], f[1]), fmaxf(f[2], f[3])),
                    fmaxf(fmaxf(f[4], f[5]), fmaxf(f[6], f[7])));
#pragma unroll
    for (int o = 32; o >= 1; o >>= 1) m = fmaxf(m, __shfl_xor(m, o));
    __shared__ float sm[4], ss[4];
    if ((t & 63) == 0) sm[t >> 6] = m;
    __syncthreads();
    m = fmaxf(fmaxf(sm[0], sm[1]), fmaxf(sm[2], sm[3]));
    float s = 0.f;
#pragma unroll
    for (int j = 0; j < 8; ++j) { f[j] = __expf(f[j] - m); s += f[j]; }
#pragma unroll
    for (int o = 32; o >= 1; o >>= 1) s += __shfl_xor(s, o);
    if ((t & 63) == 0) ss[t >> 6] = s;
    __syncthreads();
    s = (ss[0] + ss[1]) + (ss[2] + ss[3]);
    float inv = 1.f / s;
    u16x8 o8;
#pragma unroll
    for (int j = 0; j < 8; ++j) o8[j] = f2bf(f[j] * inv);
    ((u16x8*)row)[t] = o8;
}

// ======== 128x128 bf16 GEMM core (r6 K-loop + coalesced LDS-bounce epilogue) ========
// 256 thr = 4 waves (2x2), per wave 64x64 = 4x4 frags of 16x16x32. BK=64.
// LDS 32 KiB single buffer -> 3 blocks/CU. Epilogue: per-wave 16x64 slab through
// padded LDS ([16][72] rows) -> u16x8/f32x4 stores (128-256B contiguous segments
// vs 4x32B scalar-store segments of the frag-direct epilogue).
// EPI 0: QKV split + bias[col] (+fold 1/32 into Q)
// EPI 1: fp32 store   EPI 2: bf16 store   EPI 4: bf16 store + bias[ROW] (V'' fold)
template<int EPI>
__device__ __forceinline__ void gemm_core(
    u16* lds,
    const u16* __restrict__ A, const u16* __restrict__ Bt,
    int K, int ldA, int ldBt,
    const float* __restrict__ bias,
    float* __restrict__ outF, int ldOutF,
    u16* __restrict__ outH, int ldOutH,
    u16* __restrict__ Qo, u16* __restrict__ Ko, u16* __restrict__ Vo,
    int bx, int by) {
    const int tid  = threadIdx.x;
    const int lane = tid & 63;
    const int wave = tid >> 6;
    const int wrow = wave >> 1, wcol = wave & 1;
    const int lrow = lane & 15;
    const int lkg  = lane >> 4;
    const int bm0  = bx * 128;
    const int bn0  = by * 128;

    const int srow = tid >> 3;
    const int ssc  = (((tid & 7) * 16) ^ ((srow & 7) << 4)) >> 1;
    const u16* aS[4];
    const u16* bS[4];
#pragma unroll
    for (int g = 0; g < 4; ++g) {
        aS[g] = A  + (size_t)(bm0 + g * 32 + srow) * ldA  + ssc;
        bS[g] = Bt + (size_t)(bn0 + g * 32 + srow) * ldBt + ssc;
    }
    const int dst = wave * 512;

    const int sc0 = (lkg * 16) ^ ((lrow & 7) << 4);
    const int sc1 = (64 + lkg * 16) ^ ((lrow & 7) << 4);

    f32x4 acc[4][4] = {};
    const int NT = K >> 6;

    for (int t = 0; t < NT; ++t) {
#pragma unroll
        for (int g = 0; g < 4; ++g) {
            gload16(aS[g] + (size_t)t * 64, lds + g * 2048 + dst);
            gload16(bS[g] + (size_t)t * 64, lds + 8192 + g * 2048 + dst);
        }
        __syncthreads();
        const char* base = (const char*)lds;
        s16x8 ra[4][2], rb[4][2];
#pragma unroll
        for (int i = 0; i < 4; ++i) {
            const char* p = base + (wrow * 64 + i * 16 + lrow) * 128;
            ra[i][0] = *(const s16x8*)(p + sc0);
            ra[i][1] = *(const s16x8*)(p + sc1);
        }
#pragma unroll
        for (int j = 0; j < 4; ++j) {
            const char* p = base + 16384 + (wcol * 64 + j * 16 + lrow) * 128;
            rb[j][0] = *(const s16x8*)(p + sc0);
            rb[j][1] = *(const s16x8*)(p + sc1);
        }
#pragma unroll
        for (int ks = 0; ks < 2; ++ks)
#pragma unroll
            for (int i = 0; i < 4; ++i)
#pragma unroll
                for (int j = 0; j < 4; ++j)
                    acc[i][j] = __builtin_amdgcn_mfma_f32_16x16x32_bf16(
                        ra[i][ks], rb[j][ks], acc[i][j], 0, 0, 0);
        __syncthreads();                 // also frees staging LDS for the epilogue slab
    }

    // ---- coalesced epilogue (C/D frag layout: col = lane&15, row = lkg*4 + r) ----
    const int cbase0 = bn0 + wcol * 64;          // wave-uniform 64-col span
    u16* qkvOut = nullptr; int cq = cbase0; float qscale = 1.f;
    if constexpr (EPI == 0) {
        if (cbase0 < 1024)      { qkvOut = Qo; qscale = 0.03125f; }
        else if (cbase0 < 2048) { qkvOut = Ko; cq = cbase0 - 1024; }
        else                    { qkvOut = Vo; cq = cbase0 - 2048; }
    }

    if constexpr (EPI == 1) {
        float* slab = ((float*)lds) + wave * (16 * 72);
        for (int i = 0; i < 4; ++i) {
            const int row0 = bm0 + wrow * 64 + i * 16;
#pragma unroll
            for (int j = 0; j < 4; ++j)
#pragma unroll
                for (int r = 0; r < 4; ++r)
                    slab[(lkg * 4 + r) * 72 + j * 16 + lrow] = acc[i][j][r];
            const int lr0 = lane >> 4, cb = lane & 15;
#pragma unroll
            for (int b = 0; b < 4; ++b) {
                int lr = b * 4 + lr0;
                f32x4 vv = *(const f32x4*)(slab + lr * 72 + cb * 4);
                *(f32x4*)(outF + (size_t)(row0 + lr) * ldOutF + cbase0 + cb * 4) = vv;
            }
        }
    } else {
        u16* slab = lds + wave * (16 * 72);
        for (int i = 0; i < 4; ++i) {
            const int row0 = bm0 + wrow * 64 + i * 16;
#pragma unroll
            for (int j = 0; j < 4; ++j) {
                const int col = cbase0 + j * 16 + lrow;
#pragma unroll
                for (int r = 0; r < 4; ++r) {
                    float v = acc[i][j][r];
                    if constexpr (EPI == 0)      v = (v + bias[col]) * qscale;
                    else if constexpr (EPI == 4) v = v + bias[row0 + lkg * 4 + r];
                    slab[(lkg * 4 + r) * 72 + j * 16 + lrow] = f2bf(v);
                }
            }
            const int lr0 = lane >> 3, cb = lane & 7;
#pragma unroll
            for (int b = 0; b < 2; ++b) {
                int lr = b * 8 + lr0;
                u16x8 vv = *(const u16x8*)(slab + lr * 72 + cb * 8);
                u16* dp;
                if constexpr (EPI == 0) dp = qkvOut + (size_t)(row0 + lr) * 1024 + cq + cb * 8;
                else                    dp = outH + (size_t)(row0 + lr) * ldOutH + cbase0 + cb * 8;
                *(u16x8*)dp = vv;
            }
        }
    }
}

template<int EPI>
__global__ __launch_bounds__(256, 3) void gemm128(
    const u16* __restrict__ A, const u16* __restrict__ Bt,
    int K, int ldA, int ldBt,
    const float* __restrict__ bias,
    float* __restrict__ outF, int ldOutF,
    u16* __restrict__ outH, int ldOutH,
    u16* __restrict__ Qo, u16* __restrict__ Ko, u16* __restrict__ Vo,
    size_t zA, size_t zBt, size_t zOut) {
    __shared__ u16 lds[16384];
    const u16* Az  = A  + zA  * blockIdx.z;
    const u16* Btz = Bt + zBt * blockIdx.z;
    float* oF = outF; u16* oH = outH;
    if constexpr (EPI == 1) oF += zOut * blockIdx.z;
    else if constexpr (EPI == 2 || EPI == 4) oH += zOut * blockIdx.z;
    gemm_core<EPI>(lds, Az, Btz, K, ldA, ldBt, bias, oF, ldOutF, oH, ldOutH,
                   Qo, Ko, Vo, blockIdx.x, blockIdx.y);
}

extern "C" void kernel_launch(void* const* d_in, const int* in_sizes, int n_in,
                              void* d_out, int out_size, void* d_ws, size_t ws_size,
                              hipStream_t stream) {
    const float* x      = (const float*)d_in[0];
    const float* w_qkv  = (const float*)d_in[1];
    const float* b_qkv  = (const float*)d_in[2];
    const float* w_proj = (const float*)d_in[3];
    const float* b_proj = (const float*)d_in[4];
    float* out = (float*)d_out;
    char* ws = (char*)d_ws;
    (void)in_sizes; (void)n_in; (void)out_size;

    const size_t MB16  = 16777216;      // bf16 [8192][1024] bytes
    const size_t BATCH = 2097152;       // per-batch elements (2048*1024)
    const size_t SZB   = 4194304;       // per-batch S elements (2048*2048)
    const size_t VPB   = 2097152;       // per-batch V'' elements (1024*2048)

    if (ws_size >= 85983232) {
        // ---- batched plan (83.9 MB peak) ----
        // NOTE: Sb aliases Vb (+wqkvT); V'' MUST complete (separate dispatch)
        // before the S-GEMM writes Sb. Do not fuse those dispatches (r8 race).
        u16* xb     = (u16*)(ws);
        u16* Qb     = (u16*)(ws + MB16);
        u16* Kb     = (u16*)(ws + 2 * MB16);
        u16* Vb     = (u16*)(ws + 3 * MB16);
        u16* wqkvT  = (u16*)(ws + 4 * MB16);
        u16* wprojT = (u16*)(ws + 4 * MB16 + 6291456);
        u16* Vpt    = xb;                             // V''^T: 4 x [1024][2048] bf16
        u16* Sb     = Vb;                             // S: 4 x [2048][2048] bf16

        cast_f32_bf16<<<4096, 256, 0, stream>>>(x, xb, 1048576);
        transpose_cast_f32<<<dim3(96, 32), 256, 0, stream>>>(w_qkv, wqkvT, 1024, 3072);
        transpose_cast_f32<<<dim3(32, 32), 256, 0, stream>>>(w_proj, wprojT, 1024, 1024);
        // QKV: [8192,1024]x[1024,3072]
        gemm128<0><<<dim3(64, 24), 256, 0, stream>>>(xb, wqkvT, 1024, 1024, 1024,
                                                     b_qkv, nullptr, 0, nullptr, 0,
                                                     Qb, Kb, Vb, 0, 0, 0);
        // V''^T = wprojT x V + b_proj (reads Vb — before S overwrites it)
        gemm128<4><<<dim3(8, 16, 4), 256, 0, stream>>>(wprojT, Vb, 1024, 1024, 1024,
                                                       b_proj, nullptr, 0, Vpt, 2048,
                                                       nullptr, nullptr, nullptr,
                                                       0, BATCH, VPB);
        // S = Q K^T (1/32 folded into Q)
        gemm128<2><<<dim3(16, 16, 4), 256, 0, stream>>>(Qb, Kb, 1024, 1024, 1024,
                                                        nullptr, nullptr, 0, Sb, 2048,
                                                        nullptr, nullptr, nullptr,
                                                        BATCH, BATCH, SZB);
        softmax_rows_b16<<<8192, 256, 0, stream>>>(Sb);
        // out = P V'' (fp32 direct, bias folded)
        gemm128<1><<<dim3(16, 8, 4), 256, 0, stream>>>(Sb, Vpt, 2048, 2048, 2048,
                                                       nullptr, out, 1024, nullptr, 0,
                                                       nullptr, nullptr, nullptr,
                                                       SZB, VPB, BATCH);
    } else {
        // ---- low-memory per-batch plan (<=38 MB) ----
        u16* xbB    = (u16*)(ws);
        u16* QbB    = (u16*)(ws + 4194304);
        u16* KbB    = (u16*)(ws + 8388608);
        u16* VbB    = (u16*)(ws + 12582912);
        u16* VptB   = (u16*)(ws + 16777216);
        u16* Sb     = (u16*)(ws + 20971520);
        u16* wqkvT  = (u16*)(ws + 29360128);
        u16* wprojT = (u16*)(ws + 35651584);

        transpose_cast_f32<<<dim3(96, 32), 256, 0, stream>>>(w_qkv, wqkvT, 1024, 3072);
        transpose_cast_f32<<<dim3(32, 32), 256, 0, stream>>>(w_proj, wprojT, 1024, 1024);
        for (int b = 0; b < 4; ++b) {
            cast_f32_bf16<<<1024, 256, 0, stream>>>(x + (size_t)b * BATCH, xbB, 262144);
            gemm128<0><<<dim3(16, 24), 256, 0, stream>>>(xbB, wqkvT, 1024, 1024, 1024,
                                                         b_qkv, nullptr, 0, nullptr, 0,
                                                         QbB, KbB, VbB, 0, 0, 0);
            gemm128<4><<<dim3(8, 16), 256, 0, stream>>>(wprojT, VbB, 1024, 1024, 1024,
                                                        b_proj, nullptr, 0, VptB, 2048,
                                                        nullptr, nullptr, nullptr, 0, 0, 0);
            gemm128<2><<<dim3(16, 16), 256, 0, stream>>>(QbB, KbB, 1024, 1024, 1024,
                                                         nullptr, nullptr, 0, Sb, 2048,
                                                         nullptr, nullptr, nullptr, 0, 0, 0);
            softmax_rows_b16<<<2048, 256, 0, stream>>>(Sb);
            gemm128<1><<<dim3(16, 8), 256, 0, stream>>>(Sb, VptB, 2048, 2048, 2048,
                                                        nullptr, out + (size_t)b * BATCH, 1024,
                                                        nullptr, 0,
                                                        nullptr, nullptr, nullptr, 0, 0, 0);
        }
    }
}